// Round 3
// baseline (545.503 us; speedup 1.0000x reference)
//
#include <hip/hip_runtime.h>
#include <hip/hip_bf16.h>

typedef unsigned short u16;
typedef __attribute__((ext_vector_type(4))) float f32x4;
typedef __attribute__((ext_vector_type(8))) short bf16x8;
typedef __attribute__((ext_vector_type(8))) unsigned short u16x8;
typedef __attribute__((ext_vector_type(4))) unsigned short u16x4;

#define B_    64
#define T_    2048
#define HID_  512
#define HCLS_ 1024
#define DOUT_ 10
#define M_    (B_ * T_)   // 131072 rows

// ---------- helpers ----------
__device__ __forceinline__ unsigned f2bf2(float a, float b) {
#if __has_builtin(__builtin_amdgcn_cvt_pk_bf16_f32)
  auto r = __builtin_amdgcn_cvt_pk_bf16_f32(a, b);
  unsigned u;
  __builtin_memcpy(&u, &r, 4);
  return u;
#else
  unsigned ua = __float_as_uint(a) + 0x8000u;
  unsigned ub = __float_as_uint(b) + 0x8000u;
  return __builtin_amdgcn_perm(ub, ua, 0x07060302);
#endif
}

__device__ __forceinline__ float fast_tanh(float x) {
  float e = __expf(2.0f * x);
  return 1.0f - __fdividef(2.0f, e + 1.0f);
}

// ---------- kernel 0: W [k,n] fp32 -> Wt2: MFMA-B-frag-contiguous bf16 ----------
// (identical to the harness-verified Round-0 build)
// Wt2 unit = (jt, ks): 64 lanes x 16 B; lane l holds B[k0 + (l>>4)*8 ..][n = jt*16 + (l&15)]
// offset = ((jt*16 + ks)*64 + l)*8 elems -> a wave's frag load is one coalesced dwordx4.
__global__ __launch_bounds__(256) void cvt_w_kernel(const float* __restrict__ W,
                                                    u16* __restrict__ Wt2) {
  const int pair = blockIdx.x * 4 + (threadIdx.x >> 6);  // 0..511 = jt*16+ks
  const int l = threadIdx.x & 63;
  const int jt = pair >> 4, ks = pair & 15;
  const int n = jt * 16 + (l & 15);
  const int k0 = ks * 32 + (l >> 4) * 8;
  union { unsigned u[4]; u16x8 v; } r;
#pragma unroll
  for (int j = 0; j < 4; ++j)
    r.u[j] = f2bf2(W[(size_t)(k0 + 2 * j) * HID_ + n],
                   W[(size_t)(k0 + 2 * j + 1) * HID_ + n]);
  *(u16x8*)(Wt2 + (size_t)pair * 512 + l * 8) = r.v;
}

// ---------- kernel 1: fused GEMM + tanh + context-dot + exp + weighted-E partials ----------
// v2 occupancy redesign: 4096 blocks x 1024 threads (16 waves). M-tile 32, full N=512;
// wave w owns a 32x32 output tile (cols w*32..+31): acc[2][2] = 16 regs, bv0/bv1 = 16 regs,
// total ~56 regs -> __launch_bounds__(1024, 8) pins 8 waves/SIMD = 32 waves/CU (was 16,
// LDS+AGPR capped). LDS ~34 KB/block, 2 blocks/CU (wave-capped). 2x the resident waves to
// hide ds_read (~150cy) and L2 B-refill (~300cy) latency that dominated v1's 60% stall.
__global__ __launch_bounds__(1024, 8) void gemm_fused_kernel(
    const float* __restrict__ E, const u16* __restrict__ Wt2,
    const float* __restrict__ bias, const float* __restrict__ cw,
    float* __restrict__ num, float* __restrict__ den) {
  __shared__ u16 lA[32 * 512];      // 32 KB
  __shared__ float red[16 * 32];    // 2 KB
  __shared__ float earr[32];

  const int tid = threadIdx.x;
  const int m0 = blockIdx.x * 32;
  const int b = blockIdx.x >> 6;    // 64 blocks per batch element
  const int w = tid >> 6, l = tid & 63;
  const int lm = l & 15, lg = l >> 4;

  // ---- phase 1: stage 32x512 A tile (fp32 -> bf16, XOR swizzle c^(row&7)) ----
  {
    const float* ag = E + (size_t)m0 * HID_ + tid * 4;
    float4 r[4];
#pragma unroll
    for (int s = 0; s < 4; ++s)
      r[s] = *(const float4*)(ag + (size_t)s * 4096);   // all 4 in flight (16 regs)
#pragma unroll
    for (int s = 0; s < 4; ++s) {
      const int row = s * 8 + (tid >> 7);
      const int c = (tid & 127) >> 1;
      const int phys = c ^ (row & 7);
      union { unsigned u[2]; u16x4 v; } t;
      t.u[0] = f2bf2(r[s].x, r[s].y);
      t.u[1] = f2bf2(r[s].z, r[s].w);
      *(u16x4*)(lA + row * 512 + phys * 8 + (tid & 1) * 4) = t.v;
    }
  }

  // B frag base (jt = w*2 + j); prologue: ks=0 -> bv0, ks=1 -> bv1 (global: pre-barrier ok)
  const u16* bbase = Wt2 + (size_t)w * 16384 + (size_t)l * 8;
  bf16x8 bv0[2], bv1[2];
#pragma unroll
  for (int j = 0; j < 2; ++j) bv0[j] = *(const bf16x8*)(bbase + j * 8192);
#pragma unroll
  for (int j = 0; j < 2; ++j) bv1[j] = *(const bf16x8*)(bbase + j * 8192 + 512);

  __syncthreads();

  // ---- phase 2: K-loop, 8 iterations of 2 K-steps (refill distance 2 steps) ----
  f32x4 acc[2][2] = {};
#pragma unroll 1
  for (int ks = 0; ks < 16; ks += 2) {
    {   // step ks: consume bv0, refill bv0 with ks+2
      const u16* abase = lA + lm * 512 + (((ks * 4 + lg) ^ (lm & 7)) * 8);
#pragma unroll
      for (int i = 0; i < 2; ++i) {
        bf16x8 af = *(const bf16x8*)(abase + i * 16 * 512);
#pragma unroll
        for (int j = 0; j < 2; ++j)
          acc[i][j] = __builtin_amdgcn_mfma_f32_16x16x32_bf16(af, bv0[j], acc[i][j], 0, 0, 0);
      }
      if (ks + 2 < 16) {
#pragma unroll
        for (int j = 0; j < 2; ++j)
          bv0[j] = *(const bf16x8*)(bbase + j * 8192 + (size_t)(ks + 2) * 512);
      }
    }
    {   // step ks+1: consume bv1, refill bv1 with ks+3
      const u16* abase = lA + lm * 512 + ((((ks + 1) * 4 + lg) ^ (lm & 7)) * 8);
#pragma unroll
      for (int i = 0; i < 2; ++i) {
        bf16x8 af = *(const bf16x8*)(abase + i * 16 * 512);
#pragma unroll
        for (int j = 0; j < 2; ++j)
          acc[i][j] = __builtin_amdgcn_mfma_f32_16x16x32_bf16(af, bv1[j], acc[i][j], 0, 0, 0);
      }
      if (ks + 3 < 16) {
#pragma unroll
        for (int j = 0; j < 2; ++j)
          bv1[j] = *(const bf16x8*)(bbase + j * 8192 + (size_t)(ks + 3) * 512);
      }
    }
  }

  // ---- epilogue ----
  float bj[2], cj[2];
#pragma unroll
  for (int j = 0; j < 2; ++j) {
    int n = w * 32 + j * 16 + lm;
    bj[j] = bias[n];
    cj[j] = cw[n];
  }
  // per-wave 32-col partial of tanh-dot; C/D layout: col=lm, row = i*16 + lg*4 + r
#pragma unroll
  for (int i = 0; i < 2; ++i) {
#pragma unroll
    for (int r = 0; r < 4; ++r) {
      float s = 0.f;
#pragma unroll
      for (int j = 0; j < 2; ++j)
        s = fmaf(fast_tanh(acc[i][j][r] + bj[j]), cj[j], s);
      s += __shfl_xor(s, 1, 64);
      s += __shfl_xor(s, 2, 64);
      s += __shfl_xor(s, 4, 64);
      s += __shfl_xor(s, 8, 64);
      if (lm == 0) red[w * 32 + i * 16 + lg * 4 + r] = s;
    }
  }
  __syncthreads();
  if (tid < 32) {
    float d = 0.f;
#pragma unroll
    for (int ww = 0; ww < 16; ++ww) d += red[ww * 32 + tid];
    float e = __expf(fast_tanh(d));   // tanh in (-1,1): exp safe, no max-subtract
    earr[tid] = e;
    float se = e;
    se += __shfl_xor(se, 1, 64);
    se += __shfl_xor(se, 2, 64);
    se += __shfl_xor(se, 4, 64);
    se += __shfl_xor(se, 8, 64);
    se += __shfl_xor(se, 16, 64);
    if (tid == 0) atomicAdd(den + b, se);
  }
  __syncthreads();
  // num[b][col] += sum_rows e[r] * A[r][col]; lA unchanged since staging (no writes after)
  {
    const int c8 = tid >> 4, rb = tid & 15;
    const u16* nbase = lA + rb * 512 + ((c8 ^ (rb & 7)) * 8);   // phys = c8 ^ (row&7)
    float a8[8] = {};
#pragma unroll
    for (int k = 0; k < 2; ++k) {
      int r = rb + 16 * k;          // +16 keeps row&7 == rb&7
      float e = earr[r];
      u16x8 v = *(const u16x8*)(nbase + k * 16 * 512);
#pragma unroll
      for (int j = 0; j < 8; ++j)
        a8[j] = fmaf(e, __uint_as_float((unsigned)v[j] << 16), a8[j]);
    }
#pragma unroll
    for (int j = 0; j < 8; ++j) {
      a8[j] += __shfl_xor(a8[j], 1, 64);
      a8[j] += __shfl_xor(a8[j], 2, 64);
      a8[j] += __shfl_xor(a8[j], 4, 64);
      a8[j] += __shfl_xor(a8[j], 8, 64);
    }
    if (rb == 0) {
#pragma unroll
      for (int j = 0; j < 8; ++j)
        atomicAdd(num + (size_t)b * HID_ + c8 * 8 + j, a8[j]);
    }
  }
}

// ---------- kernel 2: classifier: ctx=num/den -> relu(ctx@W1+b1)@W2+b2 -> softmax(10) ----------
__global__ __launch_bounds__(1024) void classifier_kernel(
    const float* __restrict__ num, const float* __restrict__ den,
    const float* __restrict__ W1, const float* __restrict__ b1,
    const float* __restrict__ W2, const float* __restrict__ b2,
    float* __restrict__ out) {
  __shared__ float sc[HID_];
  __shared__ float hbuf[HCLS_];
  __shared__ float lgs[DOUT_];
  int b = blockIdx.x, tid = threadIdx.x;
  if (tid < HID_) sc[tid] = num[(size_t)b * HID_ + tid] / den[b];
  __syncthreads();
  float a = b1[tid];
#pragma unroll 16
  for (int k = 0; k < HID_; ++k) a = fmaf(sc[k], W1[(size_t)k * HCLS_ + tid], a);
  hbuf[tid] = fmaxf(a, 0.f);
  __syncthreads();
  if (tid < 160) {   // 10 logits x 16 lanes
    int j = tid >> 4, p = tid & 15;
    float acc2 = 0.f;
#pragma unroll 8
    for (int k = p; k < HCLS_; k += 16) acc2 = fmaf(hbuf[k], W2[(size_t)k * DOUT_ + j], acc2);
    acc2 += __shfl_xor(acc2, 1, 64);
    acc2 += __shfl_xor(acc2, 2, 64);
    acc2 += __shfl_xor(acc2, 4, 64);
    acc2 += __shfl_xor(acc2, 8, 64);
    if (p == 0) lgs[j] = acc2 + b2[j];
  }
  __syncthreads();
  if (tid == 0) {
    float mx = lgs[0];
#pragma unroll
    for (int j = 1; j < DOUT_; ++j) mx = fmaxf(mx, lgs[j]);
    float ex[DOUT_], s = 0.f;
#pragma unroll
    for (int j = 0; j < DOUT_; ++j) { ex[j] = __expf(lgs[j] - mx); s += ex[j]; }
    float inv = 1.f / s;
#pragma unroll
    for (int j = 0; j < DOUT_; ++j) out[b * DOUT_ + j] = ex[j] * inv;
  }
}

// ---------- launch ----------
extern "C" void kernel_launch(void* const* d_in, const int* in_sizes, int n_in,
                              void* d_out, int out_size, void* d_ws, size_t ws_size,
                              hipStream_t stream) {
  (void)in_sizes; (void)n_in; (void)out_size; (void)ws_size;
  const float* E    = (const float*)d_in[1];
  const float* W    = (const float*)d_in[2];
  const float* bias = (const float*)d_in[3];
  const float* cw   = (const float*)d_in[4];
  const float* W1   = (const float*)d_in[5];
  const float* b1   = (const float*)d_in[6];
  const float* W2   = (const float*)d_in[7];
  const float* b2   = (const float*)d_in[8];
  float* out = (float*)d_out;

  // ws: Wt2 512K | num 128K | den 256B  (num+den zeroed each call for the atomics)
  u16*   Wt2 = (u16*)d_ws;
  float* num = (float*)((char*)d_ws + (512 << 10));
  float* den = (float*)((char*)d_ws + (512 << 10) + B_ * HID_ * sizeof(float));

  hipMemsetAsync(num, 0, (B_ * HID_ + B_) * sizeof(float), stream);
  cvt_w_kernel<<<128, 256, 0, stream>>>(W, Wt2);
  gemm_fused_kernel<<<M_ / 32, 1024, 0, stream>>>(E, Wt2, bias, cw, num, den);
  classifier_kernel<<<B_, 1024, 0, stream>>>(num, den, W1, b1, W2, b2, out);
}

// Round 4
// 473.484 us; speedup vs baseline: 1.1521x; 1.1521x over previous
//
#include <hip/hip_runtime.h>
#include <hip/hip_bf16.h>

typedef unsigned short u16;
typedef __attribute__((ext_vector_type(4))) float f32x4;
typedef __attribute__((ext_vector_type(8))) short bf16x8;
typedef __attribute__((ext_vector_type(8))) unsigned short u16x8;
typedef __attribute__((ext_vector_type(4))) unsigned short u16x4;

#define B_    64
#define T_    2048
#define HID_  512
#define HCLS_ 1024
#define DOUT_ 10
#define M_    (B_ * T_)   // 131072 rows

// ---------- helpers ----------
__device__ __forceinline__ unsigned f2bf2(float a, float b) {
#if __has_builtin(__builtin_amdgcn_cvt_pk_bf16_f32)
  auto r = __builtin_amdgcn_cvt_pk_bf16_f32(a, b);
  unsigned u;
  __builtin_memcpy(&u, &r, 4);
  return u;
#else
  unsigned ua = __float_as_uint(a) + 0x8000u;
  unsigned ub = __float_as_uint(b) + 0x8000u;
  return __builtin_amdgcn_perm(ub, ua, 0x07060302);
#endif
}

__device__ __forceinline__ float fast_tanh(float x) {
  float e = __expf(2.0f * x);
  return 1.0f - __fdividef(2.0f, e + 1.0f);
}

// ---------- kernel 0: W [k,n] fp32 -> Wt2: MFMA-B-frag-contiguous bf16 ----------
// Wt2 unit = (jt, ks): 64 lanes x 16 B; lane l holds B[k0 + (l>>4)*8 ..][n = jt*16 + (l&15)]
// offset = ((jt*16 + ks)*64 + l)*8 elems -> a wave's frag load is one coalesced dwordx4.
__global__ __launch_bounds__(256) void cvt_w_kernel(const float* __restrict__ W,
                                                    u16* __restrict__ Wt2) {
  const int pair = blockIdx.x * 4 + (threadIdx.x >> 6);  // 0..511 = jt*16+ks
  const int l = threadIdx.x & 63;
  const int jt = pair >> 4, ks = pair & 15;
  const int n = jt * 16 + (l & 15);
  const int k0 = ks * 32 + (l >> 4) * 8;
  union { unsigned u[4]; u16x8 v; } r;
#pragma unroll
  for (int j = 0; j < 4; ++j)
    r.u[j] = f2bf2(W[(size_t)(k0 + 2 * j) * HID_ + n],
                   W[(size_t)(k0 + 2 * j + 1) * HID_ + n]);
  *(u16x8*)(Wt2 + (size_t)pair * 512 + l * 8) = r.v;
}

// ---------- kernel 1: fused GEMM + tanh + context-dot + exp + weighted-E partials ----------
// v3 intensity redesign (v2 post-mortem: per-block B-traffic is constant 512 KB, so L2
// B-stream ∝ block count; v2's 2x blocks at 85% occupancy regressed -> L2-request-bound,
// not latency-bound). M-tile 128, 1024 blocks: B-traffic 512 MB (half v1, quarter v2).
// 8 waves, wave owns 128 rows x 64 cols: acc[8][4] (~200 VGPR, 2 waves/SIMD, 1 block/CU).
// MFMA:B-load 8:1 (2x v1), MFMA:ds_read 4:1 (= v1). A staged in 8 K-chunks of 64 cols into
// DISJOINT LDS regions: chunk c+1 global loads issued before chunk c's MFMA burst (~2.5k cyc
// covers HBM latency), cvt+write after, one barrier per chunk. Full A kept in LDS for the
// weighted-E epilogue.
__global__ __launch_bounds__(512, 2) void gemm_fused_kernel(
    const float* __restrict__ E, const u16* __restrict__ Wt2,
    const float* __restrict__ bias, const float* __restrict__ cw,
    float* __restrict__ num, float* __restrict__ den) {
  __shared__ u16 lA[128 * 512];     // 128 KB (full 128x512 A tile, bf16, XOR-swizzled)
  __shared__ float red[8 * 128];    // 4 KB
  __shared__ float earr[128];

  const int tid = threadIdx.x;
  const int m0 = blockIdx.x * 128;
  const int b = blockIdx.x >> 4;    // 16 blocks per batch element (16*128 = 2048 = T)
  const int w = tid >> 6, l = tid & 63;
  const int lm = l & 15, lg = l >> 4;

  // staging map: thread -> (row0 + s*32, chunk-col4); 16 col4-quads * 32 rows * 4 s = 128x64
  const int col4 = tid & 15;        // float4 index within 64-col chunk
  const int row0 = tid >> 4;        // 0..31
  const float* eb = E + (size_t)(m0 + row0) * HID_ + col4 * 4;

  // ---- prologue: stage chunk 0 (cols 0..63) ----
  {
    float4 rg[4];
#pragma unroll
    for (int s = 0; s < 4; ++s) rg[s] = *(const float4*)(eb + (size_t)s * 32 * HID_);
#pragma unroll
    for (int s = 0; s < 4; ++s) {
      const int r = row0 + s * 32;
      const int phys = (col4 >> 1) ^ (r & 7);   // chunk 0: octets 0..7
      union { unsigned u[2]; u16x4 v; } t;
      t.u[0] = f2bf2(rg[s].x, rg[s].y);
      t.u[1] = f2bf2(rg[s].z, rg[s].w);
      *(u16x4*)(lA + r * 512 + phys * 8 + (col4 & 1) * 4) = t.v;
    }
  }

  // B frag base (jt = w*4 + j); prologue loads ks=0 -> bvA, ks=1 -> bvB (global: pre-barrier ok)
  const u16* bbase = Wt2 + (size_t)w * 32768 + (size_t)l * 8;
  bf16x8 bvA[4], bvB[4];
#pragma unroll
  for (int j = 0; j < 4; ++j) bvA[j] = *(const bf16x8*)(bbase + j * 8192);
#pragma unroll
  for (int j = 0; j < 4; ++j) bvB[j] = *(const bf16x8*)(bbase + j * 8192 + 512);

  __syncthreads();

  // ---- main loop: 8 chunks x 2 K-steps ----
  f32x4 acc[8][4] = {};
#pragma unroll 1
  for (int c = 0; c < 8; ++c) {
    // issue-early: global loads for chunk c+1 (land under this chunk's MFMA burst)
    float4 rg[4];
    if (c < 7) {
#pragma unroll
      for (int s = 0; s < 4; ++s)
        rg[s] = *(const float4*)(eb + (c + 1) * 64 + (size_t)s * 32 * HID_);
    }
    {   // K-step ks0 = 2c: consume bvA, refill bvA with ks0+2
      const int ks0 = 2 * c;
      const u16* abase = lA + lm * 512 + (((ks0 * 4 + lg) ^ (lm & 7)) * 8);
#pragma unroll
      for (int i = 0; i < 8; ++i) {
        bf16x8 af = *(const bf16x8*)(abase + i * 16 * 512);
#pragma unroll
        for (int j = 0; j < 4; ++j)
          acc[i][j] = __builtin_amdgcn_mfma_f32_16x16x32_bf16(af, bvA[j], acc[i][j], 0, 0, 0);
      }
      if (c < 7) {
#pragma unroll
        for (int j = 0; j < 4; ++j)
          bvA[j] = *(const bf16x8*)(bbase + j * 8192 + (size_t)(ks0 + 2) * 512);
      }
    }
    {   // K-step ks1 = 2c+1: consume bvB, refill bvB with ks1+2
      const int ks1 = 2 * c + 1;
      const u16* abase = lA + lm * 512 + (((ks1 * 4 + lg) ^ (lm & 7)) * 8);
#pragma unroll
      for (int i = 0; i < 8; ++i) {
        bf16x8 af = *(const bf16x8*)(abase + i * 16 * 512);
#pragma unroll
        for (int j = 0; j < 4; ++j)
          acc[i][j] = __builtin_amdgcn_mfma_f32_16x16x32_bf16(af, bvB[j], acc[i][j], 0, 0, 0);
      }
      if (c < 7) {
#pragma unroll
        for (int j = 0; j < 4; ++j)
          bvB[j] = *(const bf16x8*)(bbase + j * 8192 + (size_t)(ks1 + 2) * 512);
      }
    }
    // write-late: cvt + ds_write chunk c+1 (disjoint region: no barrier needed before writes)
    if (c < 7) {
#pragma unroll
      for (int s = 0; s < 4; ++s) {
        const int r = row0 + s * 32;
        const int phys = ((c + 1) * 8 + (col4 >> 1)) ^ (r & 7);  // XOR stays within chunk
        union { unsigned u[2]; u16x4 v; } t;
        t.u[0] = f2bf2(rg[s].x, rg[s].y);
        t.u[1] = f2bf2(rg[s].z, rg[s].w);
        *(u16x4*)(lA + r * 512 + phys * 8 + (col4 & 1) * 4) = t.v;
      }
      __syncthreads();   // chunk c+1 visible to all waves before next iteration reads it
    }
  }

  // ---- epilogue ----
  float bj[4], cj[4];
#pragma unroll
  for (int j = 0; j < 4; ++j) {
    int n = w * 64 + j * 16 + lm;
    bj[j] = bias[n];
    cj[j] = cw[n];
  }
  // per-wave 64-col partial of tanh-dot; C/D layout: col=lm, row = i*16 + lg*4 + r
#pragma unroll
  for (int i = 0; i < 8; ++i) {
#pragma unroll
    for (int r = 0; r < 4; ++r) {
      float s = 0.f;
#pragma unroll
      for (int j = 0; j < 4; ++j)
        s = fmaf(fast_tanh(acc[i][j][r] + bj[j]), cj[j], s);
      s += __shfl_xor(s, 1, 64);
      s += __shfl_xor(s, 2, 64);
      s += __shfl_xor(s, 4, 64);
      s += __shfl_xor(s, 8, 64);
      if (lm == 0) red[w * 128 + i * 16 + lg * 4 + r] = s;
    }
  }
  __syncthreads();
  if (tid < 128) {
    float d = 0.f;
#pragma unroll
    for (int ww = 0; ww < 8; ++ww) d += red[ww * 128 + tid];
    float e = __expf(fast_tanh(d));   // tanh in (-1,1): exp safe, no max-subtract
    earr[tid] = e;
    float se = e;
    se += __shfl_xor(se, 1, 64);
    se += __shfl_xor(se, 2, 64);
    se += __shfl_xor(se, 4, 64);
    se += __shfl_xor(se, 8, 64);
    se += __shfl_xor(se, 16, 64);
    se += __shfl_xor(se, 32, 64);
    if ((tid & 63) == 0) atomicAdd(den + b, se);
  }
  __syncthreads();
  // num[b][col] += sum_rows e[r] * A[r][col]; lA unchanged since staging (no writes after)
  {
    const int c8 = tid >> 3, rb = tid & 7;                 // 64 col-octets x 8 row-groups
    const u16* nbase = lA + rb * 512 + ((c8 ^ rb) * 8);    // phys = c8 ^ (row&7), row&7 == rb
    float a8[8] = {};
#pragma unroll
    for (int k = 0; k < 16; ++k) {
      int r = rb + 8 * k;
      float e = earr[r];
      u16x8 v = *(const u16x8*)(nbase + k * 8 * 512);
#pragma unroll
      for (int j = 0; j < 8; ++j)
        a8[j] = fmaf(e, __uint_as_float((unsigned)v[j] << 16), a8[j]);
    }
#pragma unroll
    for (int j = 0; j < 8; ++j) {
      a8[j] += __shfl_xor(a8[j], 1, 64);
      a8[j] += __shfl_xor(a8[j], 2, 64);
      a8[j] += __shfl_xor(a8[j], 4, 64);
    }
    if (rb == 0) {
#pragma unroll
      for (int j = 0; j < 8; ++j)
        atomicAdd(num + (size_t)b * HID_ + c8 * 8 + j, a8[j]);
    }
  }
}

// ---------- kernel 2: classifier: ctx=num/den -> relu(ctx@W1+b1)@W2+b2 -> softmax(10) ----------
__global__ __launch_bounds__(1024) void classifier_kernel(
    const float* __restrict__ num, const float* __restrict__ den,
    const float* __restrict__ W1, const float* __restrict__ b1,
    const float* __restrict__ W2, const float* __restrict__ b2,
    float* __restrict__ out) {
  __shared__ float sc[HID_];
  __shared__ float hbuf[HCLS_];
  __shared__ float lgs[DOUT_];
  int b = blockIdx.x, tid = threadIdx.x;
  if (tid < HID_) sc[tid] = num[(size_t)b * HID_ + tid] / den[b];
  __syncthreads();
  float a = b1[tid];
#pragma unroll 16
  for (int k = 0; k < HID_; ++k) a = fmaf(sc[k], W1[(size_t)k * HCLS_ + tid], a);
  hbuf[tid] = fmaxf(a, 0.f);
  __syncthreads();
  if (tid < 160) {   // 10 logits x 16 lanes
    int j = tid >> 4, p = tid & 15;
    float acc2 = 0.f;
#pragma unroll 8
    for (int k = p; k < HCLS_; k += 16) acc2 = fmaf(hbuf[k], W2[(size_t)k * DOUT_ + j], acc2);
    acc2 += __shfl_xor(acc2, 1, 64);
    acc2 += __shfl_xor(acc2, 2, 64);
    acc2 += __shfl_xor(acc2, 4, 64);
    acc2 += __shfl_xor(acc2, 8, 64);
    if (p == 0) lgs[j] = acc2 + b2[j];
  }
  __syncthreads();
  if (tid == 0) {
    float mx = lgs[0];
#pragma unroll
    for (int j = 1; j < DOUT_; ++j) mx = fmaxf(mx, lgs[j]);
    float ex[DOUT_], s = 0.f;
#pragma unroll
    for (int j = 0; j < DOUT_; ++j) { ex[j] = __expf(lgs[j] - mx); s += ex[j]; }
    float inv = 1.f / s;
#pragma unroll
    for (int j = 0; j < DOUT_; ++j) out[b * DOUT_ + j] = ex[j] * inv;
  }
}

// ---------- launch ----------
extern "C" void kernel_launch(void* const* d_in, const int* in_sizes, int n_in,
                              void* d_out, int out_size, void* d_ws, size_t ws_size,
                              hipStream_t stream) {
  (void)in_sizes; (void)n_in; (void)out_size; (void)ws_size;
  const float* E    = (const float*)d_in[1];
  const float* W    = (const float*)d_in[2];
  const float* bias = (const float*)d_in[3];
  const float* cw   = (const float*)d_in[4];
  const float* W1   = (const float*)d_in[5];
  const float* b1   = (const float*)d_in[6];
  const float* W2   = (const float*)d_in[7];
  const float* b2   = (const float*)d_in[8];
  float* out = (float*)d_out;

  // ws: Wt2 512K | num 128K | den 256B  (num+den zeroed each call for the atomics)
  u16*   Wt2 = (u16*)d_ws;
  float* num = (float*)((char*)d_ws + (512 << 10));
  float* den = (float*)((char*)d_ws + (512 << 10) + B_ * HID_ * sizeof(float));

  hipMemsetAsync(num, 0, (B_ * HID_ + B_) * sizeof(float), stream);
  cvt_w_kernel<<<128, 256, 0, stream>>>(W, Wt2);
  gemm_fused_kernel<<<M_ / 128, 512, 0, stream>>>(E, Wt2, bias, cw, num, den);
  classifier_kernel<<<B_, 1024, 0, stream>>>(num, den, W1, b1, W2, b2, out);
}